// Round 10
// baseline (173.694 us; speedup 1.0000x reference)
//
#include <hip/hip_runtime.h>
#include <hip/hip_bf16.h>
#include <stdint.h>

#define CIN 2048
#define HID 512
#define NPOS 2048
#define NNEG 2048

#define BM 256
#define BN 256
#define BK 64
#define NS 8
#define A_ELEMS (BM * BK)  // 16384

typedef __attribute__((ext_vector_type(8))) short s16x8;
typedef __attribute__((ext_vector_type(4))) short s16x4;
typedef __attribute__((ext_vector_type(4))) float f32x4;
typedef unsigned short ushort_t;

static __device__ __forceinline__ float bf2f(unsigned short u) {
    union { float f; unsigned int i; } v; v.i = ((unsigned int)u) << 16; return v.f;
}
static __device__ __forceinline__ unsigned short f2bf(float f) {
    union { float f; unsigned int i; } v; v.f = f;
    unsigned int r = v.i + 0x7FFF + ((v.i >> 16) & 1);  // RNE
    return (unsigned short)(r >> 16);
}

typedef __attribute__((address_space(1))) const void gvoid_t;
typedef __attribute__((address_space(3))) void lvoid_t;
static __device__ __forceinline__ void gload16(const void* g, void* l) {
    __builtin_amdgcn_global_load_lds((gvoid_t*)g, (lvoid_t*)l, 16, 0, 0);
}

// ============ pass 1 (fused): NCHW->NHWC bf16, W transpose, border zero ============
__global__ __launch_bounds__(256) void k_prep(const float* __restrict__ F,
                                              const float* __restrict__ W1,
                                              ushort_t* __restrict__ Fp,
                                              ushort_t* __restrict__ Wt2) {
    __shared__ float tile[64][17];
    __shared__ float buf[512 * 9];
    int bid = blockIdx.x;
    int t = threadIdx.x;
    if (bid < 256) {
        int b = bid >> 4, y = bid & 15;
        for (int ic0 = 0; ic0 < CIN; ic0 += 64) {
            {   // read 64 ci x 16 x, float4 per thread
                int ci = t >> 2, xg = t & 3;
                const float4 v = *(const float4*)&F[((size_t)(b * CIN + ic0 + ci) * 16 + y) * 16 + xg * 4];
                tile[ci][xg * 4 + 0] = v.x;
                tile[ci][xg * 4 + 1] = v.y;
                tile[ci][xg * 4 + 2] = v.z;
                tile[ci][xg * 4 + 3] = v.w;
            }
            __syncthreads();
            {   // write 16 x x 64 ci, 4 bf16 (8B) per thread
                int x = t >> 4, cig = t & 15;
                s16x4 o;
#pragma unroll
                for (int j = 0; j < 4; ++j) o[j] = (short)f2bf(tile[cig * 4 + j][x]);
                *(s16x4*)&Fp[((size_t)(b * 18 + y + 1) * 18 + (x + 1)) * CIN + ic0 + cig * 4] = o;
            }
            __syncthreads();
        }
    } else if (bid < 768) {
        int oc = bid - 256;
        for (int ic0 = 0; ic0 < CIN; ic0 += 512) {
            const float* src = W1 + ((size_t)oc * CIN + ic0) * 9;
            {   // bulk float4 load: 4608 floats = 1152 float4
                const float4* s4 = (const float4*)src;
                float4* b4 = (float4*)buf;
                for (int i = t; i < 1152; i += 256) b4[i] = s4[i];
            }
            __syncthreads();
            for (int s = t; s < 9 * 64; s += 256) {  // 16B store per (k, 8-ic group)
                int k = s >> 6, g = s & 63;
                s16x8 v;
#pragma unroll
                for (int j = 0; j < 8; ++j) v[j] = (short)f2bf(buf[(g * 8 + j) * 9 + k]);
                *(s16x8*)&Wt2[((size_t)(k * HID + oc)) * CIN + ic0 + g * 8] = v;
            }
            __syncthreads();
        }
    } else {
        // zero the 68 border cells per image
        const s16x8 z = {0, 0, 0, 0, 0, 0, 0, 0};
        for (int idx = (bid - 768) * 256 + t; idx < 16 * 68 * 256; idx += 64 * 256) {
            int seg = idx & 255;
            int cell = (idx >> 8) % 68;
            int b = idx / (68 * 256);
            int Y, X;
            if (cell < 18)      { Y = 0;         X = cell; }
            else if (cell < 36) { Y = 17;        X = cell - 18; }
            else if (cell < 52) { Y = cell - 35; X = 0; }
            else                { Y = cell - 51; X = 17; }
            *(s16x8*)&Fp[((size_t)(b * 18 + Y) * 18 + X) * CIN + seg * 8] = z;
        }
    }
}

// ============ pass 2: split-K implicit-GEMM, 256x256x64 ============
// 512 thr = 8 waves (2M x 4N), wave tile 128x64. A: 3-buffer LDS (96 KB), counted
// vmcnt(4) end-of-step (A(t+1) gets ~1.5 steps of flight). B: DIRECT from L2 to
// registers per wave (no LDS) — B slice shared by 16 blocks, L2-hot. B loads are
// issued FIRST each step (oldest in vmcnt order) so the compiler's pre-MFMA B-wait
// leaves the A-prefetch outstanding.
__global__ __launch_bounds__(512, 2) void k_gemm(const ushort_t* __restrict__ Fp,
                                                 const ushort_t* __restrict__ Wt2,
                                                 ushort_t* __restrict__ Part,
                                                 int icLen, int nPairs) {
    extern __shared__ ushort_t ldsbuf[];
    ushort_t* As = ldsbuf;   // [3][A_ELEMS]

    int bid = blockIdx.x;
    int rb = bid / nPairs;
    int pair = bid - rb * nPairs;   // pair%8 spreads (split,cb) groups across XCDs
    int split = pair >> 1, cb = pair & 1;
    int icBase = split * icLen;
    int m0 = rb * BM, oc0 = cb * BN;
    int t = threadIdx.x;
    int wid = t >> 6, lane = t & 63;
    int wr = wid >> 2, wn = wid & 3;   // 2 x 4 wave grid, wave tile 128x64
    int hi = lane >> 4, lo = lane & 15;

    f32x4 acc[8][4];
#pragma unroll
    for (int a = 0; a < 8; ++a)
#pragma unroll
        for (int b = 0; b < 4; ++b) acc[a][b] = (f32x4){0.f, 0.f, 0.f, 0.f};

    // A staging bases (pre-swizzled global 16B segment; LDS dest linear — rule #21)
    int Abase[4];
#pragma unroll
    for (int j = 0; j < 4; ++j) {
        int li = j * 512 + t;             // [0,2048)
        int row = li >> 3;                // 0..255
        int sg = (li & 7) ^ (row & 7);
        int m = m0 + row;
        int b = m >> 8, y = (m >> 4) & 15, x = m & 15;
        Abase[j] = ((b * 18 + y) * 18 + x) * CIN + sg * 8;
    }
    // A ds_read swizzled indices
    int aidx[8][2];
#pragma unroll
    for (int fm = 0; fm < 8; ++fm)
#pragma unroll
        for (int ks = 0; ks < 2; ++ks) {
            int r = wr * 128 + fm * 16 + lo;
            aidx[fm][ks] = r * BK + ((ks * 32 + hi * 8) ^ ((r & 7) << 3));
        }
    // B per-lane row base (direct global reads)
    int bRowBase = (oc0 + wn * 64 + lo) * CIN + hi * 8;

    const int nsteps = (icLen / BK) * 9;  // 36 at NS=8; kidx inner, ic-chunk outer

#define STAGE_A(BUF, S)                                                              \
    do {                                                                             \
        int kidx_ = (S) % 9, icc_ = (S) / 9;                                         \
        int ak_ = ((kidx_ / 3) * 18 + (kidx_ - 3 * (kidx_ / 3))) * CIN + icBase + icc_ * BK; \
        ushort_t* dA_ = As + (BUF) * A_ELEMS;                                        \
        _Pragma("unroll") for (int j_ = 0; j_ < 4; ++j_)                             \
            gload16(Fp + Abase[j_] + ak_, dA_ + (size_t)(j_ * 512 + t) * 8);         \
    } while (0)

    // prologue: A tiles 0,1 in flight; tile 0 ready across all waves
    STAGE_A(0, 0); STAGE_A(1, 1);
    asm volatile("s_waitcnt vmcnt(4)" ::: "memory");
    __builtin_amdgcn_s_barrier();
    __builtin_amdgcn_sched_barrier(0);

    int bi = 0;
#pragma unroll 1
    for (int step = 0; step < nsteps; ++step) {
        const ushort_t* cA = As + bi * A_ELEMS;
        int b2 = (bi >= 1) ? bi - 1 : 2;  // (bi+2)%3
        int kidx = step % 9, icc = step / 9;
        int bpos = kidx * HID * CIN + icBase + icc * BK;

        // ---- B loads FIRST (oldest in vmcnt): 8 x s16x8 direct from L2
        s16x8 bf[4][2];
#pragma unroll
        for (int fn = 0; fn < 4; ++fn)
#pragma unroll
            for (int ks = 0; ks < 2; ++ks)
                bf[fn][ks] = *(const s16x8*)&Wt2[(size_t)bpos + bRowBase + fn * 16 * CIN + ks * 32];
        // ---- then A prefetch for step+2
        if (step + 2 < nsteps) STAGE_A(b2, step + 2);
        // ---- A fragments from LDS
        s16x8 af[8][2];
#pragma unroll
        for (int fm = 0; fm < 8; ++fm)
#pragma unroll
            for (int ks = 0; ks < 2; ++ks) af[fm][ks] = *(const s16x8*)&cA[aidx[fm][ks]];
        __builtin_amdgcn_s_setprio(1);
#pragma unroll
        for (int fm = 0; fm < 8; ++fm)
#pragma unroll
            for (int fn = 0; fn < 4; ++fn)
#pragma unroll
                for (int ks = 0; ks < 2; ++ks)
                    acc[fm][fn] = __builtin_amdgcn_mfma_f32_16x16x32_bf16(
                        af[fm][ks], bf[fn][ks], acc[fm][fn], 0, 0, 0);
        __builtin_amdgcn_s_setprio(0);
        // ---- end-of-step: A(step+1) ready across all waves (counted: A(step+2) may fly)
        if (step + 2 < nsteps) {
            asm volatile("s_waitcnt vmcnt(4)" ::: "memory");
            __builtin_amdgcn_s_barrier();
            __builtin_amdgcn_sched_barrier(0);
        } else if (step + 1 < nsteps) {
            asm volatile("s_waitcnt vmcnt(0)" ::: "memory");
            __builtin_amdgcn_s_barrier();
            __builtin_amdgcn_sched_barrier(0);
        }
        bi = (bi == 2) ? 0 : bi + 1;
    }
#undef STAGE_A

    // epilogue: store bf16 partials
#pragma unroll
    for (int fm = 0; fm < 8; ++fm)
#pragma unroll
        for (int fn = 0; fn < 4; ++fn)
#pragma unroll
            for (int r = 0; r < 4; ++r) {
                int gm = m0 + wr * 128 + fm * 16 + hi * 4 + r;
                int gn = oc0 + wn * 64 + fn * 16 + lo;
                Part[((size_t)split * 4096 + gm) * HID + gn] = f2bf(acc[fm][fn][r]);
            }
}

// ============ pass 3: reduce bf16 splits + bias + ReLU + MFMA 1x1 heads ============
__global__ __launch_bounds__(256) void k_heads(const ushort_t* __restrict__ Part, int ns,
                                               const float* __restrict__ b1,
                                               const float* __restrict__ Wc,
                                               const float* __restrict__ bc,
                                               const float* __restrict__ Wr,
                                               const float* __restrict__ br,
                                               float* __restrict__ conf,
                                               float* __restrict__ reg) {
    extern __shared__ ushort_t hsm[];
    ushort_t* Ah = hsm;              // [16][512] bf16, XOR-swizzled (16 KB)
    ushort_t* Wh = hsm + 16 * HID;   // [48][512] bf16, XOR-swizzled (48 KB)
    int t = threadIdx.x;
    int wid = t >> 6, lane = t & 63;
    int hi = lane >> 4, lo = lane & 15;
    int row0 = blockIdx.x * 16;

    // stage hidden: sum bf16 splits + bias + relu -> bf16 swizzled (16B units)
#pragma unroll
    for (int i = 0; i < 4; ++i) {
        int pos = i * 256 + t;           // [0,1024): 16 rows x 64 segs
        int r = pos >> 6, sg = pos & 63;
        float s[8];
#pragma unroll
        for (int j = 0; j < 8; ++j) s[j] = 0.f;
        for (int sp = 0; sp < ns; ++sp) {
            s16x8 v = *(const s16x8*)&Part[((size_t)sp * 4096 + row0 + r) * HID + sg * 8];
#pragma unroll
            for (int j = 0; j < 8; ++j) s[j] += bf2f((unsigned short)v[j]);
        }
        s16x8 o;
#pragma unroll
        for (int j = 0; j < 8; ++j) o[j] = (short)f2bf(fmaxf(s[j] + b1[sg * 8 + j], 0.f));
        *(s16x8*)&Ah[r * HID + ((sg ^ (r & 7)) << 3)] = o;
    }
    // stage head weights (rows 0-8: Wc, 9-44: Wr, 45-47: zero)
#pragma unroll
    for (int i = 0; i < 12; ++i) {
        int sid = i * 256 + t;           // [0,3072)
        int o = sid >> 6, sg = sid & 63;
        s16x8 v;
#pragma unroll
        for (int j = 0; j < 8; ++j) {
            float w = 0.f;
            if (o < 9) w = Wc[o * HID + sg * 8 + j];
            else if (o < 45) w = Wr[(size_t)(o - 9) * HID + sg * 8 + j];
            v[j] = (short)f2bf(w);
        }
        *(s16x8*)&Wh[o * HID + ((sg ^ (o & 7)) << 3)] = v;
    }
    __syncthreads();
    if (wid != 0) return;

    f32x4 acc[3];
#pragma unroll
    for (int fn = 0; fn < 3; ++fn) acc[fn] = (f32x4){0.f, 0.f, 0.f, 0.f};
#pragma unroll 1
    for (int kf = 0; kf < 16; ++kf) {
        int rA = lo;
        s16x8 a_ = *(const s16x8*)&Ah[rA * HID + ((kf * 32 + hi * 8) ^ ((rA & 7) << 3))];
#pragma unroll
        for (int fn = 0; fn < 3; ++fn) {
            int rB = fn * 16 + lo;
            s16x8 b_ = *(const s16x8*)&Wh[rB * HID + ((kf * 32 + hi * 8) ^ ((rB & 7) << 3))];
            acc[fn] = __builtin_amdgcn_mfma_f32_16x16x32_bf16(a_, b_, acc[fn], 0, 0, 0);
        }
    }
#pragma unroll
    for (int fn = 0; fn < 3; ++fn)
#pragma unroll
        for (int r = 0; r < 4; ++r) {
            int gm = row0 + hi * 4 + r;
            int o = fn * 16 + lo;
            float v = acc[fn][r];
            if (o < 9) conf[gm * 9 + o] = v + bc[o];
            else if (o < 45) reg[gm * 36 + (o - 9)] = v + br[o - 9];
        }
}

// ============ pass 4: gathers + proposals + losses ============
static __device__ __forceinline__ float softplus(float x) {
    return log1pf(expf(-fabsf(x))) + fmaxf(x, 0.f);
}

__global__ __launch_bounds__(1024) void k_loss(const float* __restrict__ conf,
                                               const float* __restrict__ reg,
                                               const int* __restrict__ pos_ind,
                                               const int* __restrict__ neg_ind,
                                               const float* __restrict__ anc,
                                               const float* __restrict__ gt,
                                               float* __restrict__ out) {
    int t = threadIdx.x;
    float cls = 0.f, rloss = 0.f;
    for (int p = t; p < NPOS; p += 1024) {
        int ind = pos_ind[p];
        {  // conf gather: flat index over [B,9,16,16]
            int b = ind / 2304, r = ind % 2304;
            int c = r >> 8, r2 = r & 255;
            float cv = conf[(b * 256 + r2) * 9 + c];
            cls += softplus(-cv);
        }
        float off[4];
#pragma unroll
        for (int j = 0; j < 4; ++j) {  // reg.reshape(-1,4)[ind]
            int e = 4 * ind + j;
            int b = e / 9216, r = e % 9216;
            int c = r >> 8, r2 = r & 255;
            off[j] = reg[(b * 256 + r2) * 36 + c];
        }
        float ax1 = anc[4 * p], ay1 = anc[4 * p + 1], ax2 = anc[4 * p + 2], ay2 = anc[4 * p + 3];
        float acx = (ax1 + ax2) * 0.5f, acy = (ay1 + ay2) * 0.5f;
        float aw = ax2 - ax1, ah = ay2 - ay1;
        float pcx = acx + off[0] * aw, pcy = acy + off[1] * ah;
        float pw = aw * expf(off[2]), ph = ah * expf(off[3]);
        out[1 + 4 * p + 0] = pcx - pw * 0.5f;
        out[1 + 4 * p + 1] = pcy - ph * 0.5f;
        out[1 + 4 * p + 2] = pcx + pw * 0.5f;
        out[1 + 4 * p + 3] = pcy + ph * 0.5f;
        float gx1 = gt[4 * p], gy1 = gt[4 * p + 1], gx2 = gt[4 * p + 2], gy2 = gt[4 * p + 3];
        float gcx = (gx1 + gx2) * 0.5f, gcy = (gy1 + gy2) * 0.5f;
        float gw = gx2 - gx1, gh = gy2 - gy1;
        float tv[4];
        tv[0] = (gcx - acx) / aw;
        tv[1] = (gcy - acy) / ah;
        tv[2] = logf(gw / aw);
        tv[3] = logf(gh / ah);
#pragma unroll
        for (int j = 0; j < 4; ++j) {
            float d = off[j] - tv[j];
            float ad = fabsf(d);
            rloss += (ad < 1.f) ? 0.5f * d * d : ad - 0.5f;
        }
    }
    for (int q = t; q < NNEG; q += 1024) {
        int ind = neg_ind[q];
        int b = ind / 2304, r = ind % 2304;
        int c = r >> 8, r2 = r & 255;
        float cv = conf[(b * 256 + r2) * 9 + c];
        cls += softplus(cv);
    }
    __shared__ float s1[1024], s2[1024];
    s1[t] = cls;
    s2[t] = rloss;
    __syncthreads();
    for (int s = 512; s > 0; s >>= 1) {
        if (t < s) {
            s1[t] += s1[t + s];
            s2[t] += s2[t + s];
        }
        __syncthreads();
    }
    if (t == 0) out[0] = (s1[0] + 5.f * s2[0]) / 16.f;
}

extern "C" void kernel_launch(void* const* d_in, const int* in_sizes, int n_in,
                              void* d_out, int out_size, void* d_ws, size_t ws_size,
                              hipStream_t stream) {
    const float* F   = (const float*)d_in[0];
    const float* anc = (const float*)d_in[1];
    const float* gt  = (const float*)d_in[2];
    const float* W1  = (const float*)d_in[3];
    const float* b1  = (const float*)d_in[4];
    const float* Wc  = (const float*)d_in[5];
    const float* bc  = (const float*)d_in[6];
    const float* Wr  = (const float*)d_in[7];
    const float* br  = (const float*)d_in[8];
    const int* pos_ind = (const int*)d_in[9];
    const int* neg_ind = (const int*)d_in[10];
    float* out = (float*)d_out;

    char* ws = (char*)d_ws;
    const size_t FP_BYTES   = (size_t)16 * 18 * 18 * CIN * 2;  // 21,233,664
    const size_t WT_BYTES   = (size_t)9 * HID * CIN * 2;       // 18,874,368
    const size_t PART_ONE   = (size_t)4096 * HID * 2;          // 4 MB per split (bf16)
    const size_t CONF_BYTES = (size_t)4096 * 9 * 4;

    int icLen = CIN / NS;  // 256

    ushort_t* Fp   = (ushort_t*)ws;
    ushort_t* Wt2  = (ushort_t*)(ws + FP_BYTES);
    ushort_t* Part = (ushort_t*)(ws + FP_BYTES + WT_BYTES);
    float* conf    = (float*)(ws + FP_BYTES + WT_BYTES + (size_t)NS * PART_ONE);
    float* reg     = (float*)(ws + FP_BYTES + WT_BYTES + (size_t)NS * PART_ONE + CONF_BYTES);

    const int GEMM_LDS = 3 * A_ELEMS * 2;  // 98304
    hipFuncSetAttribute((const void*)k_gemm, hipFuncAttributeMaxDynamicSharedMemorySize, GEMM_LDS);
    const int HEADS_LDS = (16 + 48) * HID * 2;  // 65536
    hipFuncSetAttribute((const void*)k_heads, hipFuncAttributeMaxDynamicSharedMemorySize, HEADS_LDS);

    k_prep<<<832, 256, 0, stream>>>(F, W1, Fp, Wt2);
    k_gemm<<<(4096 / BM) * (HID / BN) * NS, 512, GEMM_LDS, stream>>>(Fp, Wt2, Part, icLen, 2 * NS);
    k_heads<<<256, 256, HEADS_LDS, stream>>>(Part, NS, b1, Wc, bc, Wr, br, conf, reg);
    k_loss<<<1, 1024, 0, stream>>>(conf, reg, pos_ind, neg_ind, anc, gt, out);
}

// Round 11
// 127.479 us; speedup vs baseline: 1.3625x; 1.3625x over previous
//
#include <hip/hip_runtime.h>
#include <hip/hip_bf16.h>
#include <stdint.h>

#define CIN 2048
#define HID 512
#define NPOS 2048
#define NNEG 2048

#define BM 256
#define BN 256
#define BK 64
#define NS 8
#define A_ELEMS (BM * BK)  // 16384
#define B_ELEMS (BN * BK)  // 16384

typedef __attribute__((ext_vector_type(8))) short s16x8;
typedef __attribute__((ext_vector_type(4))) short s16x4;
typedef __attribute__((ext_vector_type(4))) float f32x4;
typedef unsigned short ushort_t;

static __device__ __forceinline__ float bf2f(unsigned short u) {
    union { float f; unsigned int i; } v; v.i = ((unsigned int)u) << 16; return v.f;
}
static __device__ __forceinline__ unsigned short f2bf(float f) {
    union { float f; unsigned int i; } v; v.f = f;
    unsigned int r = v.i + 0x7FFF + ((v.i >> 16) & 1);  // RNE
    return (unsigned short)(r >> 16);
}

typedef __attribute__((address_space(1))) const void gvoid_t;
typedef __attribute__((address_space(3))) void lvoid_t;
static __device__ __forceinline__ void gload16(const void* g, void* l) {
    __builtin_amdgcn_global_load_lds((gvoid_t*)g, (lvoid_t*)l, 16, 0, 0);
}

// ============ pass 1 (fused): NCHW->NHWC bf16, W transpose, border zero ============
// fmap: 1024 blocks, each (b,y,icq) does 8 ic-chunks (4 blocks/CU, latency overlap).
__global__ __launch_bounds__(256) void k_prep(const float* __restrict__ F,
                                              const float* __restrict__ W1,
                                              ushort_t* __restrict__ Fp,
                                              ushort_t* __restrict__ Wt2) {
    __shared__ float tile[64][17];
    __shared__ float buf[512 * 9];
    int bid = blockIdx.x;
    int t = threadIdx.x;
    if (bid < 1024) {
        int b = bid >> 6, rem = bid & 63;
        int y = rem >> 2, icq = rem & 3;
        for (int i = 0; i < 8; ++i) {
            int ic0 = icq * 512 + i * 64;
            {   // read 64 ci x 16 x, float4 per thread
                int ci = t >> 2, xg = t & 3;
                const float4 v = *(const float4*)&F[((size_t)(b * CIN + ic0 + ci) * 16 + y) * 16 + xg * 4];
                tile[ci][xg * 4 + 0] = v.x;
                tile[ci][xg * 4 + 1] = v.y;
                tile[ci][xg * 4 + 2] = v.z;
                tile[ci][xg * 4 + 3] = v.w;
            }
            __syncthreads();
            {   // write 16 x x 64 ci, 4 bf16 (8B) per thread
                int x = t >> 4, cig = t & 15;
                s16x4 o;
#pragma unroll
                for (int j = 0; j < 4; ++j) o[j] = (short)f2bf(tile[cig * 4 + j][x]);
                *(s16x4*)&Fp[((size_t)(b * 18 + y + 1) * 18 + (x + 1)) * CIN + ic0 + cig * 4] = o;
            }
            __syncthreads();
        }
    } else if (bid < 1536) {
        int oc = bid - 1024;
        for (int ic0 = 0; ic0 < CIN; ic0 += 512) {
            const float* src = W1 + ((size_t)oc * CIN + ic0) * 9;
            {   // bulk float4 load: 4608 floats = 1152 float4
                const float4* s4 = (const float4*)src;
                float4* b4 = (float4*)buf;
                for (int i = t; i < 1152; i += 256) b4[i] = s4[i];
            }
            __syncthreads();
            for (int s = t; s < 9 * 64; s += 256) {  // 16B store per (k, 8-ic group)
                int k = s >> 6, g = s & 63;
                s16x8 v;
#pragma unroll
                for (int j = 0; j < 8; ++j) v[j] = (short)f2bf(buf[(g * 8 + j) * 9 + k]);
                *(s16x8*)&Wt2[((size_t)(k * HID + oc)) * CIN + ic0 + g * 8] = v;
            }
            __syncthreads();
        }
    } else {
        // zero the 68 border cells per image
        const s16x8 z = {0, 0, 0, 0, 0, 0, 0, 0};
        for (int idx = (bid - 1536) * 256 + t; idx < 16 * 68 * 256; idx += 64 * 256) {
            int seg = idx & 255;
            int cell = (idx >> 8) % 68;
            int b = idx / (68 * 256);
            int Y, X;
            if (cell < 18)      { Y = 0;         X = cell; }
            else if (cell < 36) { Y = 17;        X = cell - 18; }
            else if (cell < 52) { Y = cell - 35; X = 0; }
            else                { Y = cell - 51; X = 17; }
            *(s16x8*)&Fp[((size_t)(b * 18 + Y) * 18 + X) * CIN + seg * 8] = z;
        }
    }
}

// ============ pass 2: split-K implicit-GEMM, 256x256x64 (R7 proven structure) ============
// 512 thr = 8 waves (2M x 4N), wave tile 128x64. 2-buffer LDS (128 KB dynamic).
// 2-phase: STAGE(t+1) at step top -> ds_read/MFMA -> vmcnt(0)+s_barrier at step end.
__global__ __launch_bounds__(512, 2) void k_gemm(const ushort_t* __restrict__ Fp,
                                                 const ushort_t* __restrict__ Wt2,
                                                 ushort_t* __restrict__ Part,
                                                 int icLen, int nPairs) {
    extern __shared__ ushort_t ldsbuf[];
    ushort_t* As = ldsbuf;                 // [2][A_ELEMS]
    ushort_t* Bs = ldsbuf + 2 * A_ELEMS;   // [2][B_ELEMS]

    int bid = blockIdx.x;
    int rb = bid / nPairs;
    int pair = bid - rb * nPairs;   // pair%8 spreads (split,cb) groups across XCDs
    int split = pair >> 1, cb = pair & 1;
    int icBase = split * icLen;
    int m0 = rb * BM, oc0 = cb * BN;
    int t = threadIdx.x;
    int wid = t >> 6, lane = t & 63;
    int wr = wid >> 2, wn = wid & 3;   // 2 x 4 wave grid, wave tile 128x64
    int hi = lane >> 4, lo = lane & 15;

    f32x4 acc[8][4];
#pragma unroll
    for (int a = 0; a < 8; ++a)
#pragma unroll
        for (int b = 0; b < 4; ++b) acc[a][b] = (f32x4){0.f, 0.f, 0.f, 0.f};

    // staging bases (pre-swizzled global 16B segment; LDS dest linear — rule #21)
    int Abase[4], Bbase[4];
#pragma unroll
    for (int j = 0; j < 4; ++j) {
        int li = j * 512 + t;             // [0,2048)
        int row = li >> 3;                // 0..255
        int sg = (li & 7) ^ (row & 7);
        int m = m0 + row;
        int b = m >> 8, y = (m >> 4) & 15, x = m & 15;
        Abase[j] = ((b * 18 + y) * 18 + x) * CIN + sg * 8;
        Bbase[j] = (oc0 + row) * CIN + sg * 8;
    }
    // swizzled ds_read element indices
    int aidx[8][2], bidx[4][2];
#pragma unroll
    for (int fm = 0; fm < 8; ++fm)
#pragma unroll
        for (int ks = 0; ks < 2; ++ks) {
            int r = wr * 128 + fm * 16 + lo;
            aidx[fm][ks] = r * BK + ((ks * 32 + hi * 8) ^ ((r & 7) << 3));
        }
#pragma unroll
    for (int fn = 0; fn < 4; ++fn)
#pragma unroll
        for (int ks = 0; ks < 2; ++ks) {
            int rB = wn * 64 + fn * 16 + lo;
            bidx[fn][ks] = rB * BK + ((ks * 32 + hi * 8) ^ ((rB & 7) << 3));
        }

    const int nsteps = (icLen / BK) * 9;  // 36 at NS=8; kidx inner, ic-chunk outer

#define STAGE(BUF, S)                                                                \
    do {                                                                             \
        int kidx_ = (S) % 9, icc_ = (S) / 9;                                         \
        int ak_ = ((kidx_ / 3) * 18 + (kidx_ - 3 * (kidx_ / 3))) * CIN + icBase + icc_ * BK; \
        int bk_ = kidx_ * HID * CIN + icBase + icc_ * BK;                            \
        ushort_t* dA_ = As + (BUF) * A_ELEMS;                                        \
        ushort_t* dB_ = Bs + (BUF) * B_ELEMS;                                        \
        _Pragma("unroll") for (int j_ = 0; j_ < 4; ++j_) {                           \
            gload16(Fp + Abase[j_] + ak_, dA_ + (size_t)(j_ * 512 + t) * 8);         \
            gload16(Wt2 + Bbase[j_] + bk_, dB_ + (size_t)(j_ * 512 + t) * 8);        \
        }                                                                            \
    } while (0)

    // prologue: tile 0 staged and visible to all waves
    STAGE(0, 0);
    asm volatile("s_waitcnt vmcnt(0)" ::: "memory");
    __builtin_amdgcn_s_barrier();
    __builtin_amdgcn_sched_barrier(0);

    int cur = 0;
#pragma unroll 1
    for (int step = 0; step < nsteps; ++step) {
        const ushort_t* cA = As + cur * A_ELEMS;
        const ushort_t* cB = Bs + cur * B_ELEMS;
        // issue next-tile staging first (DMA; hides under this step's compute)
        if (step + 1 < nsteps) STAGE(cur ^ 1, step + 1);
        // ds_reads + MFMA (compiler auto fine-grained lgkmcnt)
        s16x8 af[8][2], bf[4][2];
#pragma unroll
        for (int ks = 0; ks < 2; ++ks) {
#pragma unroll
            for (int fm = 0; fm < 8; ++fm) af[fm][ks] = *(const s16x8*)&cA[aidx[fm][ks]];
#pragma unroll
            for (int fn = 0; fn < 4; ++fn) bf[fn][ks] = *(const s16x8*)&cB[bidx[fn][ks]];
        }
        __builtin_amdgcn_s_setprio(1);
#pragma unroll
        for (int fm = 0; fm < 8; ++fm)
#pragma unroll
            for (int fn = 0; fn < 4; ++fn)
#pragma unroll
                for (int ks = 0; ks < 2; ++ks)
                    acc[fm][fn] = __builtin_amdgcn_mfma_f32_16x16x32_bf16(
                        af[fm][ks], bf[fn][ks], acc[fm][fn], 0, 0, 0);
        __builtin_amdgcn_s_setprio(0);
        // end-of-step handshake: next tile staged by ALL waves; cur buffer free
        if (step + 1 < nsteps) {
            asm volatile("s_waitcnt vmcnt(0)" ::: "memory");
            __builtin_amdgcn_s_barrier();
            __builtin_amdgcn_sched_barrier(0);
        }
        cur ^= 1;
    }
#undef STAGE

    // epilogue: store bf16 partials
#pragma unroll
    for (int fm = 0; fm < 8; ++fm)
#pragma unroll
        for (int fn = 0; fn < 4; ++fn)
#pragma unroll
            for (int r = 0; r < 4; ++r) {
                int gm = m0 + wr * 128 + fm * 16 + hi * 4 + r;
                int gn = oc0 + wn * 64 + fn * 16 + lo;
                Part[((size_t)split * 4096 + gm) * HID + gn] = f2bf(acc[fm][fn][r]);
            }
}

// ============ pass 3: reduce bf16 splits + bias + ReLU + MFMA 1x1 heads ============
__global__ __launch_bounds__(256) void k_heads(const ushort_t* __restrict__ Part, int ns,
                                               const float* __restrict__ b1,
                                               const float* __restrict__ Wc,
                                               const float* __restrict__ bc,
                                               const float* __restrict__ Wr,
                                               const float* __restrict__ br,
                                               float* __restrict__ conf,
                                               float* __restrict__ reg) {
    extern __shared__ ushort_t hsm[];
    ushort_t* Ah = hsm;              // [16][512] bf16, XOR-swizzled (16 KB)
    ushort_t* Wh = hsm + 16 * HID;   // [48][512] bf16, XOR-swizzled (48 KB)
    int t = threadIdx.x;
    int wid = t >> 6, lane = t & 63;
    int hi = lane >> 4, lo = lane & 15;
    int row0 = blockIdx.x * 16;

    // stage hidden: sum bf16 splits + bias + relu -> bf16 swizzled (16B units)
#pragma unroll
    for (int i = 0; i < 4; ++i) {
        int pos = i * 256 + t;           // [0,1024): 16 rows x 64 segs
        int r = pos >> 6, sg = pos & 63;
        float s[8];
#pragma unroll
        for (int j = 0; j < 8; ++j) s[j] = 0.f;
        for (int sp = 0; sp < ns; ++sp) {
            s16x8 v = *(const s16x8*)&Part[((size_t)sp * 4096 + row0 + r) * HID + sg * 8];
#pragma unroll
            for (int j = 0; j < 8; ++j) s[j] += bf2f((unsigned short)v[j]);
        }
        s16x8 o;
#pragma unroll
        for (int j = 0; j < 8; ++j) o[j] = (short)f2bf(fmaxf(s[j] + b1[sg * 8 + j], 0.f));
        *(s16x8*)&Ah[r * HID + ((sg ^ (r & 7)) << 3)] = o;
    }
    // stage head weights (rows 0-8: Wc, 9-44: Wr, 45-47: zero)
#pragma unroll
    for (int i = 0; i < 12; ++i) {
        int sid = i * 256 + t;           // [0,3072)
        int o = sid >> 6, sg = sid & 63;
        s16x8 v;
#pragma unroll
        for (int j = 0; j < 8; ++j) {
            float w = 0.f;
            if (o < 9) w = Wc[o * HID + sg * 8 + j];
            else if (o < 45) w = Wr[(size_t)(o - 9) * HID + sg * 8 + j];
            v[j] = (short)f2bf(w);
        }
        *(s16x8*)&Wh[o * HID + ((sg ^ (o & 7)) << 3)] = v;
    }
    __syncthreads();
    if (wid != 0) return;

    f32x4 acc[3];
#pragma unroll
    for (int fn = 0; fn < 3; ++fn) acc[fn] = (f32x4){0.f, 0.f, 0.f, 0.f};
#pragma unroll 1
    for (int kf = 0; kf < 16; ++kf) {
        int rA = lo;
        s16x8 a_ = *(const s16x8*)&Ah[rA * HID + ((kf * 32 + hi * 8) ^ ((rA & 7) << 3))];
#pragma unroll
        for (int fn = 0; fn < 3; ++fn) {
            int rB = fn * 16 + lo;
            s16x8 b_ = *(const s16x8*)&Wh[rB * HID + ((kf * 32 + hi * 8) ^ ((rB & 7) << 3))];
            acc[fn] = __builtin_amdgcn_mfma_f32_16x16x32_bf16(a_, b_, acc[fn], 0, 0, 0);
        }
    }
#pragma unroll
    for (int fn = 0; fn < 3; ++fn)
#pragma unroll
        for (int r = 0; r < 4; ++r) {
            int gm = row0 + hi * 4 + r;
            int o = fn * 16 + lo;
            float v = acc[fn][r];
            if (o < 9) conf[gm * 9 + o] = v + bc[o];
            else if (o < 45) reg[gm * 36 + (o - 9)] = v + br[o - 9];
        }
}

// ============ pass 4: gathers + proposals + losses ============
static __device__ __forceinline__ float softplus(float x) {
    return log1pf(expf(-fabsf(x))) + fmaxf(x, 0.f);
}

__global__ __launch_bounds__(1024) void k_loss(const float* __restrict__ conf,
                                               const float* __restrict__ reg,
                                               const int* __restrict__ pos_ind,
                                               const int* __restrict__ neg_ind,
                                               const float* __restrict__ anc,
                                               const float* __restrict__ gt,
                                               float* __restrict__ out) {
    int t = threadIdx.x;
    float cls = 0.f, rloss = 0.f;
    for (int p = t; p < NPOS; p += 1024) {
        int ind = pos_ind[p];
        {  // conf gather: flat index over [B,9,16,16]
            int b = ind / 2304, r = ind % 2304;
            int c = r >> 8, r2 = r & 255;
            float cv = conf[(b * 256 + r2) * 9 + c];
            cls += softplus(-cv);
        }
        float off[4];
#pragma unroll
        for (int j = 0; j < 4; ++j) {  // reg.reshape(-1,4)[ind]
            int e = 4 * ind + j;
            int b = e / 9216, r = e % 9216;
            int c = r >> 8, r2 = r & 255;
            off[j] = reg[(b * 256 + r2) * 36 + c];
        }
        float ax1 = anc[4 * p], ay1 = anc[4 * p + 1], ax2 = anc[4 * p + 2], ay2 = anc[4 * p + 3];
        float acx = (ax1 + ax2) * 0.5f, acy = (ay1 + ay2) * 0.5f;
        float aw = ax2 - ax1, ah = ay2 - ay1;
        float pcx = acx + off[0] * aw, pcy = acy + off[1] * ah;
        float pw = aw * expf(off[2]), ph = ah * expf(off[3]);
        out[1 + 4 * p + 0] = pcx - pw * 0.5f;
        out[1 + 4 * p + 1] = pcy - ph * 0.5f;
        out[1 + 4 * p + 2] = pcx + pw * 0.5f;
        out[1 + 4 * p + 3] = pcy + ph * 0.5f;
        float gx1 = gt[4 * p], gy1 = gt[4 * p + 1], gx2 = gt[4 * p + 2], gy2 = gt[4 * p + 3];
        float gcx = (gx1 + gx2) * 0.5f, gcy = (gy1 + gy2) * 0.5f;
        float gw = gx2 - gx1, gh = gy2 - gy1;
        float tv[4];
        tv[0] = (gcx - acx) / aw;
        tv[1] = (gcy - acy) / ah;
        tv[2] = logf(gw / aw);
        tv[3] = logf(gh / ah);
#pragma unroll
        for (int j = 0; j < 4; ++j) {
            float d = off[j] - tv[j];
            float ad = fabsf(d);
            rloss += (ad < 1.f) ? 0.5f * d * d : ad - 0.5f;
        }
    }
    for (int q = t; q < NNEG; q += 1024) {
        int ind = neg_ind[q];
        int b = ind / 2304, r = ind % 2304;
        int c = r >> 8, r2 = r & 255;
        float cv = conf[(b * 256 + r2) * 9 + c];
        cls += softplus(cv);
    }
    __shared__ float s1[1024], s2[1024];
    s1[t] = cls;
    s2[t] = rloss;
    __syncthreads();
    for (int s = 512; s > 0; s >>= 1) {
        if (t < s) {
            s1[t] += s1[t + s];
            s2[t] += s2[t + s];
        }
        __syncthreads();
    }
    if (t == 0) out[0] = (s1[0] + 5.f * s2[0]) / 16.f;
}

extern "C" void kernel_launch(void* const* d_in, const int* in_sizes, int n_in,
                              void* d_out, int out_size, void* d_ws, size_t ws_size,
                              hipStream_t stream) {
    const float* F   = (const float*)d_in[0];
    const float* anc = (const float*)d_in[1];
    const float* gt  = (const float*)d_in[2];
    const float* W1  = (const float*)d_in[3];
    const float* b1  = (const float*)d_in[4];
    const float* Wc  = (const float*)d_in[5];
    const float* bc  = (const float*)d_in[6];
    const float* Wr  = (const float*)d_in[7];
    const float* br  = (const float*)d_in[8];
    const int* pos_ind = (const int*)d_in[9];
    const int* neg_ind = (const int*)d_in[10];
    float* out = (float*)d_out;

    char* ws = (char*)d_ws;
    const size_t FP_BYTES   = (size_t)16 * 18 * 18 * CIN * 2;  // 21,233,664
    const size_t WT_BYTES   = (size_t)9 * HID * CIN * 2;       // 18,874,368
    const size_t PART_ONE   = (size_t)4096 * HID * 2;          // 4 MB per split (bf16)
    const size_t CONF_BYTES = (size_t)4096 * 9 * 4;

    int icLen = CIN / NS;  // 256

    ushort_t* Fp   = (ushort_t*)ws;
    ushort_t* Wt2  = (ushort_t*)(ws + FP_BYTES);
    ushort_t* Part = (ushort_t*)(ws + FP_BYTES + WT_BYTES);
    float* conf    = (float*)(ws + FP_BYTES + WT_BYTES + (size_t)NS * PART_ONE);
    float* reg     = (float*)(ws + FP_BYTES + WT_BYTES + (size_t)NS * PART_ONE + CONF_BYTES);

    const int GEMM_LDS = 2 * (A_ELEMS + B_ELEMS) * 2;  // 131072
    hipFuncSetAttribute((const void*)k_gemm, hipFuncAttributeMaxDynamicSharedMemorySize, GEMM_LDS);
    const int HEADS_LDS = (16 + 48) * HID * 2;         // 65536
    hipFuncSetAttribute((const void*)k_heads, hipFuncAttributeMaxDynamicSharedMemorySize, HEADS_LDS);

    k_prep<<<1600, 256, 0, stream>>>(F, W1, Fp, Wt2);
    k_gemm<<<(4096 / BM) * (HID / BN) * NS, 512, GEMM_LDS, stream>>>(Fp, Wt2, Part, icLen, 2 * NS);
    k_heads<<<256, 256, HEADS_LDS, stream>>>(Part, NS, b1, Wc, bc, Wr, br, conf, reg);
    k_loss<<<1, 1024, 0, stream>>>(conf, reg, pos_ind, neg_ind, anc, gt, out);
}

// Round 12
// 125.150 us; speedup vs baseline: 1.3879x; 1.0186x over previous
//
#include <hip/hip_runtime.h>
#include <hip/hip_bf16.h>
#include <stdint.h>

#define CIN 2048
#define HID 512
#define NPOS 2048
#define NNEG 2048

#define BM 256
#define BN 256
#define BK 64
#define NS 8
#define A_ELEMS (BM * BK)  // 16384
#define B_ELEMS (BN * BK)  // 16384

typedef __attribute__((ext_vector_type(8))) short s16x8;
typedef __attribute__((ext_vector_type(4))) short s16x4;
typedef __attribute__((ext_vector_type(4))) float f32x4;
typedef unsigned short ushort_t;

static __device__ __forceinline__ float bf2f(unsigned short u) {
    union { float f; unsigned int i; } v; v.i = ((unsigned int)u) << 16; return v.f;
}
static __device__ __forceinline__ unsigned short f2bf(float f) {
    union { float f; unsigned int i; } v; v.f = f;
    unsigned int r = v.i + 0x7FFF + ((v.i >> 16) & 1);  // RNE
    return (unsigned short)(r >> 16);
}

typedef __attribute__((address_space(1))) const void gvoid_t;
typedef __attribute__((address_space(3))) void lvoid_t;
static __device__ __forceinline__ void gload16(const void* g, void* l) {
    __builtin_amdgcn_global_load_lds((gvoid_t*)g, (lvoid_t*)l, 16, 0, 0);
}

// ============ pass 1 (fused): NCHW->NHWC bf16, W transpose, border zero, head-W pack ============
__global__ __launch_bounds__(256) void k_prep(const float* __restrict__ F,
                                              const float* __restrict__ W1,
                                              const float* __restrict__ Wc,
                                              const float* __restrict__ Wr,
                                              ushort_t* __restrict__ Fp,
                                              ushort_t* __restrict__ Wt2,
                                              ushort_t* __restrict__ Whp) {
    __shared__ float tile[128][17];   // 8.7 KB
    __shared__ float buf[512 * 9];    // 18.4 KB
    int bid = blockIdx.x;
    int t = threadIdx.x;
    if (bid < 1024) {
        int b = bid >> 6, rem = bid & 63;
        int y = rem >> 2, icq = rem & 3;
        for (int it = 0; it < 4; ++it) {
            int ic0 = icq * 512 + it * 128;
#pragma unroll
            for (int i2 = 0; i2 < 2; ++i2) {   // read 128 ci x 16 x, float4/thread
                int idx = i2 * 256 + t;
                int ci = idx >> 2, xg = idx & 3;
                const float4 v = *(const float4*)&F[((size_t)(b * CIN + ic0 + ci) * 16 + y) * 16 + xg * 4];
                tile[ci][xg * 4 + 0] = v.x;
                tile[ci][xg * 4 + 1] = v.y;
                tile[ci][xg * 4 + 2] = v.z;
                tile[ci][xg * 4 + 3] = v.w;
            }
            __syncthreads();
#pragma unroll
            for (int i2 = 0; i2 < 2; ++i2) {   // write 16 x x 128 ci, 8B/thread
                int idx = i2 * 256 + t;
                int x = idx >> 5, cig = idx & 31;
                s16x4 o;
#pragma unroll
                for (int j = 0; j < 4; ++j) o[j] = (short)f2bf(tile[cig * 4 + j][x]);
                *(s16x4*)&Fp[((size_t)(b * 18 + y + 1) * 18 + (x + 1)) * CIN + ic0 + cig * 4] = o;
            }
            __syncthreads();
        }
    } else if (bid < 1536) {
        int oc = bid - 1024;
        for (int ic0 = 0; ic0 < CIN; ic0 += 512) {
            const float* src = W1 + ((size_t)oc * CIN + ic0) * 9;
            {   // bulk float4 load: 4608 floats = 1152 float4
                const float4* s4 = (const float4*)src;
                float4* b4 = (float4*)buf;
                for (int i = t; i < 1152; i += 256) b4[i] = s4[i];
            }
            __syncthreads();
            for (int s = t; s < 9 * 64; s += 256) {  // 16B store per (k, 8-ic group)
                int k = s >> 6, g = s & 63;
                s16x8 v;
#pragma unroll
                for (int j = 0; j < 8; ++j) v[j] = (short)f2bf(buf[(g * 8 + j) * 9 + k]);
                *(s16x8*)&Wt2[((size_t)(k * HID + oc)) * CIN + ic0 + g * 8] = v;
            }
            __syncthreads();
        }
    } else if (bid < 1600) {
        // zero the 68 border cells per image
        const s16x8 z = {0, 0, 0, 0, 0, 0, 0, 0};
        for (int idx = (bid - 1536) * 256 + t; idx < 16 * 68 * 256; idx += 64 * 256) {
            int seg = idx & 255;
            int cell = (idx >> 8) % 68;
            int b = idx / (68 * 256);
            int Y, X;
            if (cell < 18)      { Y = 0;         X = cell; }
            else if (cell < 36) { Y = 17;        X = cell - 18; }
            else if (cell < 52) { Y = cell - 35; X = 0; }
            else                { Y = cell - 51; X = 17; }
            *(s16x8*)&Fp[((size_t)(b * 18 + Y) * 18 + X) * CIN + seg * 8] = z;
        }
    } else {
        // head-weight pre-pack: Whp[48][512] bf16, XOR-pre-swizzled (rows 45-47 zero)
#pragma unroll
        for (int i = 0; i < 12; ++i) {
            int sid = i * 256 + t;           // [0,3072)
            int o = sid >> 6, sg = sid & 63;
            s16x8 v;
#pragma unroll
            for (int j = 0; j < 8; ++j) {
                float w = 0.f;
                if (o < 9) w = Wc[o * HID + sg * 8 + j];
                else if (o < 45) w = Wr[(size_t)(o - 9) * HID + sg * 8 + j];
                v[j] = (short)f2bf(w);
            }
            *(s16x8*)&Whp[o * HID + ((sg ^ (o & 7)) << 3)] = v;
        }
    }
}

// ============ pass 2: split-K implicit-GEMM, 256x256x64, counted 3A/2B pipeline ============
// 512 thr = 8 waves (2M x 4N), wave tile 128x64. A: 3-buffer, B: 2-buffer = 160 KB LDS.
// Per step: issue B(s+1) at TOP, A(s+2) mid-step; end-of-step vmcnt(4)+s_barrier retires
// exactly {A(s+1), B(s+1)} while A(s+2) stays in flight — staging DMA never idles.
__global__ __launch_bounds__(512, 2) void k_gemm(const ushort_t* __restrict__ Fp,
                                                 const ushort_t* __restrict__ Wt2,
                                                 ushort_t* __restrict__ Part,
                                                 int icLen, int nPairs) {
    extern __shared__ ushort_t ldsbuf[];
    ushort_t* As = ldsbuf;                 // [3][A_ELEMS]
    ushort_t* Bs = ldsbuf + 3 * A_ELEMS;   // [2][B_ELEMS]

    int bid = blockIdx.x;
    int rb = bid / nPairs;
    int pair = bid - rb * nPairs;   // pair%8 spreads (split,cb) groups across XCDs
    int split = pair >> 1, cb = pair & 1;
    int icBase = split * icLen;
    int m0 = rb * BM, oc0 = cb * BN;
    int t = threadIdx.x;
    int wid = t >> 6, lane = t & 63;
    int wr = wid >> 2, wn = wid & 3;   // 2 x 4 wave grid, wave tile 128x64
    int hi = lane >> 4, lo = lane & 15;

    f32x4 acc[8][4];
#pragma unroll
    for (int a = 0; a < 8; ++a)
#pragma unroll
        for (int b = 0; b < 4; ++b) acc[a][b] = (f32x4){0.f, 0.f, 0.f, 0.f};

    // staging bases (pre-swizzled global 16B segment; LDS dest linear — rule #21)
    int Abase[4], Bbase[4];
#pragma unroll
    for (int j = 0; j < 4; ++j) {
        int li = j * 512 + t;             // [0,2048)
        int row = li >> 3;                // 0..255
        int sg = (li & 7) ^ (row & 7);
        int m = m0 + row;
        int b = m >> 8, y = (m >> 4) & 15, x = m & 15;
        Abase[j] = ((b * 18 + y) * 18 + x) * CIN + sg * 8;
        Bbase[j] = (oc0 + row) * CIN + sg * 8;
    }
    // swizzled ds_read element indices
    int aidx[8][2], bidx[4][2];
#pragma unroll
    for (int fm = 0; fm < 8; ++fm)
#pragma unroll
        for (int ks = 0; ks < 2; ++ks) {
            int r = wr * 128 + fm * 16 + lo;
            aidx[fm][ks] = r * BK + ((ks * 32 + hi * 8) ^ ((r & 7) << 3));
        }
#pragma unroll
    for (int fn = 0; fn < 4; ++fn)
#pragma unroll
        for (int ks = 0; ks < 2; ++ks) {
            int rB = wn * 64 + fn * 16 + lo;
            bidx[fn][ks] = rB * BK + ((ks * 32 + hi * 8) ^ ((rB & 7) << 3));
        }

    const int nsteps = (icLen / BK) * 9;  // 36 at NS=8; kidx inner, ic-chunk outer

#define STAGE_A(BUF, S)                                                              \
    do {                                                                             \
        int kidx_ = (S) % 9, icc_ = (S) / 9;                                         \
        int ak_ = ((kidx_ / 3) * 18 + (kidx_ - 3 * (kidx_ / 3))) * CIN + icBase + icc_ * BK; \
        ushort_t* dA_ = As + (BUF) * A_ELEMS;                                        \
        _Pragma("unroll") for (int j_ = 0; j_ < 4; ++j_)                             \
            gload16(Fp + Abase[j_] + ak_, dA_ + (size_t)(j_ * 512 + t) * 8);         \
    } while (0)
#define STAGE_B(BUF, S)                                                              \
    do {                                                                             \
        int kidx_ = (S) % 9, icc_ = (S) / 9;                                         \
        int bk_ = kidx_ * HID * CIN + icBase + icc_ * BK;                            \
        ushort_t* dB_ = Bs + (BUF) * B_ELEMS;                                        \
        _Pragma("unroll") for (int j_ = 0; j_ < 4; ++j_)                             \
            gload16(Wt2 + Bbase[j_] + bk_, dB_ + (size_t)(j_ * 512 + t) * 8);        \
    } while (0)

    // prologue: A(0),B(0),A(1) issued; vmcnt(4) retires A(0),B(0); barrier = tile 0 ready
    STAGE_A(0, 0); STAGE_B(0, 0); STAGE_A(1, 1);
    asm volatile("s_waitcnt vmcnt(4)" ::: "memory");
    __builtin_amdgcn_s_barrier();
    __builtin_amdgcn_sched_barrier(0);

#pragma unroll 1
    for (int step = 0; step < nsteps; ++step) {
        const ushort_t* cA = As + (step % 3) * A_ELEMS;
        const ushort_t* cB = Bs + (step & 1) * B_ELEMS;
        // B(s+1) at TOP (oldest loads of this step; full step of flight time)
        if (step + 1 < nsteps) STAGE_B((step + 1) & 1, step + 1);
        // ds_reads + MFMA (compiler auto fine-grained lgkmcnt)
        s16x8 af[8][2], bf[4][2];
#pragma unroll
        for (int ks = 0; ks < 2; ++ks) {
#pragma unroll
            for (int fm = 0; fm < 8; ++fm) af[fm][ks] = *(const s16x8*)&cA[aidx[fm][ks]];
#pragma unroll
            for (int fn = 0; fn < 4; ++fn) bf[fn][ks] = *(const s16x8*)&cB[bidx[fn][ks]];
        }
        // A(s+2) mid-step (gets ~1.5 steps of flight; stays in flight across barrier)
        if (step + 2 < nsteps) STAGE_A((step + 2) % 3, step + 2);
        __builtin_amdgcn_s_setprio(1);
#pragma unroll
        for (int fm = 0; fm < 8; ++fm)
#pragma unroll
            for (int fn = 0; fn < 4; ++fn)
#pragma unroll
                for (int ks = 0; ks < 2; ++ks)
                    acc[fm][fn] = __builtin_amdgcn_mfma_f32_16x16x32_bf16(
                        af[fm][ks], bf[fn][ks], acc[fm][fn], 0, 0, 0);
        __builtin_amdgcn_s_setprio(0);
        // end-of-step: retire A(s+1),B(s+1) across all waves; A(s+2) keeps flying
        if (step + 2 < nsteps) {
            asm volatile("s_waitcnt vmcnt(4)" ::: "memory");
            __builtin_amdgcn_s_barrier();
            __builtin_amdgcn_sched_barrier(0);
        } else if (step + 1 < nsteps) {
            asm volatile("s_waitcnt vmcnt(0)" ::: "memory");
            __builtin_amdgcn_s_barrier();
            __builtin_amdgcn_sched_barrier(0);
        }
    }
#undef STAGE_A
#undef STAGE_B

    // epilogue: store bf16 partials
#pragma unroll
    for (int fm = 0; fm < 8; ++fm)
#pragma unroll
        for (int fn = 0; fn < 4; ++fn)
#pragma unroll
            for (int r = 0; r < 4; ++r) {
                int gm = m0 + wr * 128 + fm * 16 + hi * 4 + r;
                int gn = oc0 + wn * 64 + fn * 16 + lo;
                Part[((size_t)split * 4096 + gm) * HID + gn] = f2bf(acc[fm][fn][r]);
            }
}

// ============ pass 3: reduce bf16 splits + bias + ReLU + MFMA 1x1 heads ============
__global__ __launch_bounds__(256) void k_heads(const ushort_t* __restrict__ Part, int ns,
                                               const ushort_t* __restrict__ Whp,
                                               const float* __restrict__ b1,
                                               const float* __restrict__ bc,
                                               const float* __restrict__ br,
                                               float* __restrict__ conf,
                                               float* __restrict__ reg) {
    extern __shared__ ushort_t hsm[];
    ushort_t* Ah = hsm;              // [16][512] bf16, XOR-swizzled (16 KB)
    ushort_t* Wh = hsm + 16 * HID;   // [48][512] bf16, XOR-swizzled (48 KB)
    int t = threadIdx.x;
    int wid = t >> 6, lane = t & 63;
    int hi = lane >> 4, lo = lane & 15;
    int row0 = blockIdx.x * 16;

    // stage head weights: straight DMA from pre-packed Whp (linear, pre-swizzled)
#pragma unroll
    for (int i = 0; i < 12; ++i)
        gload16(Whp + (size_t)(i * 256 + t) * 8, Wh + (size_t)(i * 256 + t) * 8);

    // stage hidden: sum bf16 splits + bias + relu -> bf16 swizzled (16B units)
#pragma unroll
    for (int i = 0; i < 4; ++i) {
        int pos = i * 256 + t;           // [0,1024): 16 rows x 64 segs
        int r = pos >> 6, sg = pos & 63;
        float s[8];
#pragma unroll
        for (int j = 0; j < 8; ++j) s[j] = 0.f;
        for (int sp = 0; sp < ns; ++sp) {
            s16x8 v = *(const s16x8*)&Part[((size_t)sp * 4096 + row0 + r) * HID + sg * 8];
#pragma unroll
            for (int j = 0; j < 8; ++j) s[j] += bf2f((unsigned short)v[j]);
        }
        s16x8 o;
#pragma unroll
        for (int j = 0; j < 8; ++j) o[j] = (short)f2bf(fmaxf(s[j] + b1[sg * 8 + j], 0.f));
        *(s16x8*)&Ah[r * HID + ((sg ^ (r & 7)) << 3)] = o;
    }
    __syncthreads();   // drains vmcnt+lgkmcnt: Wh DMA and Ah writes visible
    if (wid != 0) return;

    f32x4 acc[3];
#pragma unroll
    for (int fn = 0; fn < 3; ++fn) acc[fn] = (f32x4){0.f, 0.f, 0.f, 0.f};
#pragma unroll 1
    for (int kf = 0; kf < 16; ++kf) {
        int rA = lo;
        s16x8 a_ = *(const s16x8*)&Ah[rA * HID + ((kf * 32 + hi * 8) ^ ((rA & 7) << 3))];
#pragma unroll
        for (int fn = 0; fn < 3; ++fn) {
            int rB = fn * 16 + lo;
            s16x8 b_ = *(const s16x8*)&Wh[rB * HID + ((kf * 32 + hi * 8) ^ ((rB & 7) << 3))];
            acc[fn] = __builtin_amdgcn_mfma_f32_16x16x32_bf16(a_, b_, acc[fn], 0, 0, 0);
        }
    }
#pragma unroll
    for (int fn = 0; fn < 3; ++fn)
#pragma unroll
        for (int r = 0; r < 4; ++r) {
            int gm = row0 + hi * 4 + r;
            int o = fn * 16 + lo;
            float v = acc[fn][r];
            if (o < 9) conf[gm * 9 + o] = v + bc[o];
            else if (o < 45) reg[gm * 36 + (o - 9)] = v + br[o - 9];
        }
}

// ============ pass 4: gathers + proposals + losses ============
static __device__ __forceinline__ float softplus(float x) {
    return log1pf(expf(-fabsf(x))) + fmaxf(x, 0.f);
}

__global__ __launch_bounds__(1024) void k_loss(const float* __restrict__ conf,
                                               const float* __restrict__ reg,
                                               const int* __restrict__ pos_ind,
                                               const int* __restrict__ neg_ind,
                                               const float* __restrict__ anc,
                                               const float* __restrict__ gt,
                                               float* __restrict__ out) {
    int t = threadIdx.x;
    float cls = 0.f, rloss = 0.f;
    for (int p = t; p < NPOS; p += 1024) {
        int ind = pos_ind[p];
        {  // conf gather: flat index over [B,9,16,16]
            int b = ind / 2304, r = ind % 2304;
            int c = r >> 8, r2 = r & 255;
            float cv = conf[(b * 256 + r2) * 9 + c];
            cls += softplus(-cv);
        }
        float off[4];
#pragma unroll
        for (int j = 0; j < 4; ++j) {  // reg.reshape(-1,4)[ind]
            int e = 4 * ind + j;
            int b = e / 9216, r = e % 9216;
            int c = r >> 8, r2 = r & 255;
            off[j] = reg[(b * 256 + r2) * 36 + c];
        }
        float ax1 = anc[4 * p], ay1 = anc[4 * p + 1], ax2 = anc[4 * p + 2], ay2 = anc[4 * p + 3];
        float acx = (ax1 + ax2) * 0.5f, acy = (ay1 + ay2) * 0.5f;
        float aw = ax2 - ax1, ah = ay2 - ay1;
        float pcx = acx + off[0] * aw, pcy = acy + off[1] * ah;
        float pw = aw * expf(off[2]), ph = ah * expf(off[3]);
        out[1 + 4 * p + 0] = pcx - pw * 0.5f;
        out[1 + 4 * p + 1] = pcy - ph * 0.5f;
        out[1 + 4 * p + 2] = pcx + pw * 0.5f;
        out[1 + 4 * p + 3] = pcy + ph * 0.5f;
        float gx1 = gt[4 * p], gy1 = gt[4 * p + 1], gx2 = gt[4 * p + 2], gy2 = gt[4 * p + 3];
        float gcx = (gx1 + gx2) * 0.5f, gcy = (gy1 + gy2) * 0.5f;
        float gw = gx2 - gx1, gh = gy2 - gy1;
        float tv[4];
        tv[0] = (gcx - acx) / aw;
        tv[1] = (gcy - acy) / ah;
        tv[2] = logf(gw / aw);
        tv[3] = logf(gh / ah);
#pragma unroll
        for (int j = 0; j < 4; ++j) {
            float d = off[j] - tv[j];
            float ad = fabsf(d);
            rloss += (ad < 1.f) ? 0.5f * d * d : ad - 0.5f;
        }
    }
    for (int q = t; q < NNEG; q += 1024) {
        int ind = neg_ind[q];
        int b = ind / 2304, r = ind % 2304;
        int c = r >> 8, r2 = r & 255;
        float cv = conf[(b * 256 + r2) * 9 + c];
        cls += softplus(cv);
    }
    __shared__ float s1[1024], s2[1024];
    s1[t] = cls;
    s2[t] = rloss;
    __syncthreads();
    for (int s = 512; s > 0; s >>= 1) {
        if (t < s) {
            s1[t] += s1[t + s];
            s2[t] += s2[t + s];
        }
        __syncthreads();
    }
    if (t == 0) out[0] = (s1[0] + 5.f * s2[0]) / 16.f;
}

extern "C" void kernel_launch(void* const* d_in, const int* in_sizes, int n_in,
                              void* d_out, int out_size, void* d_ws, size_t ws_size,
                              hipStream_t stream) {
    const float* F   = (const float*)d_in[0];
    const float* anc = (const float*)d_in[1];
    const float* gt  = (const float*)d_in[2];
    const float* W1  = (const float*)d_in[3];
    const float* b1  = (const float*)d_in[4];
    const float* Wc  = (const float*)d_in[5];
    const float* bc  = (const float*)d_in[6];
    const float* Wr  = (const float*)d_in[7];
    const float* br  = (const float*)d_in[8];
    const int* pos_ind = (const int*)d_in[9];
    const int* neg_ind = (const int*)d_in[10];
    float* out = (float*)d_out;

    char* ws = (char*)d_ws;
    const size_t FP_BYTES   = (size_t)16 * 18 * 18 * CIN * 2;  // 21,233,664
    const size_t WT_BYTES   = (size_t)9 * HID * CIN * 2;       // 18,874,368
    const size_t PART_ONE   = (size_t)4096 * HID * 2;          // 4 MB per split (bf16)
    const size_t CONF_BYTES = (size_t)4096 * 9 * 4;
    const size_t REG_BYTES  = (size_t)4096 * 36 * 4;

    int icLen = CIN / NS;  // 256

    ushort_t* Fp   = (ushort_t*)ws;
    ushort_t* Wt2  = (ushort_t*)(ws + FP_BYTES);
    ushort_t* Part = (ushort_t*)(ws + FP_BYTES + WT_BYTES);
    float* conf    = (float*)(ws + FP_BYTES + WT_BYTES + (size_t)NS * PART_ONE);
    float* reg     = (float*)(ws + FP_BYTES + WT_BYTES + (size_t)NS * PART_ONE + CONF_BYTES);
    ushort_t* Whp  = (ushort_t*)(ws + FP_BYTES + WT_BYTES + (size_t)NS * PART_ONE + CONF_BYTES + REG_BYTES);

    const int GEMM_LDS = (3 * A_ELEMS + 2 * B_ELEMS) * 2;  // 163840 = full 160 KB
    hipFuncSetAttribute((const void*)k_gemm, hipFuncAttributeMaxDynamicSharedMemorySize, GEMM_LDS);
    const int HEADS_LDS = (16 + 48) * HID * 2;             // 65536
    hipFuncSetAttribute((const void*)k_heads, hipFuncAttributeMaxDynamicSharedMemorySize, HEADS_LDS);

    k_prep<<<1601, 256, 0, stream>>>(F, W1, Wc, Wr, Fp, Wt2, Whp);
    k_gemm<<<(4096 / BM) * (HID / BN) * NS, 512, GEMM_LDS, stream>>>(Fp, Wt2, Part, icLen, 2 * NS);
    k_heads<<<256, 256, HEADS_LDS, stream>>>(Part, NS, Whp, b1, bc, br, conf, reg);
    k_loss<<<1, 1024, 0, stream>>>(conf, reg, pos_ind, neg_ind, anc, gt, out);
}